// Round 2
// baseline (913.362 us; speedup 1.0000x reference)
//
#include <hip/hip_runtime.h>
#include <math.h>

#define NN 100000      // nodes
#define CD 32          // classes / hidden
#define NPB 4          // nodes per block in fused layer kernel (1 wave each)

// ---------------------------------------------------------------------------
// Detect whether edge_index is int64 or int32 on-device (JAX x64-off makes it
// int32 despite the reference saying int64). If the first 512 values read as
// int64 are all in [0, NN), it's int64.
__global__ void detect_idx64(const void* edge, int* flag) {
    const long long* p = (const long long*)edge;
    int ok = 1;
    for (int i = 0; i < 512; ++i) {
        long long v = p[i];
        if (v < 0 || v >= NN) { ok = 0; break; }
    }
    *flag = ok;
}

__device__ __forceinline__ int load_idx(const void* edge, int i, int is64) {
    if (is64) return (int)((const long long*)edge)[i];
    return ((const int*)edge)[i];
}

// ---------------------------------------------------------------------------
// CSR build: histogram of dst, exclusive scan, then scatter src ids.
// NOTE: `cursor` aliases `counts` (scan reads counts[i] before writing
// cursor[i] in the same thread+iteration — safe, saves 400 KB of ws).
__global__ void hist_kernel(const void* edge, int E, const int* flag, int* counts) {
    int e = blockIdx.x * blockDim.x + threadIdx.x;
    if (e >= E) return;
    int is64 = *flag;
    int dst = load_idx(edge, E + e, is64);
    atomicAdd(&counts[dst], 1);
}

__global__ void scan_kernel(const int* __restrict__ counts,
                            int* __restrict__ offsets,
                            int* __restrict__ cursor) {
    __shared__ int partial[256];
    const int t = threadIdx.x;
    const int chunk = (NN + 255) / 256;   // 391
    int begin = t * chunk;
    int end   = begin + chunk; if (end > NN) end = NN;
    int s = 0;
    for (int i = begin; i < end; ++i) s += counts[i];
    partial[t] = s;
    __syncthreads();
    if (t == 0) {
        int run = 0;
        for (int i = 0; i < 256; ++i) { int c = partial[i]; partial[i] = run; run += c; }
    }
    __syncthreads();
    int run = partial[t];
    for (int i = begin; i < end; ++i) {
        int c = counts[i];          // read BEFORE cursor write (cursor may alias)
        offsets[i] = run;
        cursor[i]  = run;
        run += c;
    }
    if (end == NN) offsets[NN] = run;   // == E
}

__global__ void fill_kernel(const void* edge, int E, const int* flag,
                            int* cursor, int* __restrict__ csr_src) {
    int e = blockIdx.x * blockDim.x + threadIdx.x;
    if (e >= E) return;
    int is64 = *flag;
    int s = load_idx(edge, e, is64);
    int d = load_idx(edge, E + e, is64);
    int pos = atomicAdd(&cursor[d], 1);
    csr_src[pos] = s;
}

// ---------------------------------------------------------------------------
// Fused SAGE layer: gather-max over neighbors + dual dense (+ optional relu /
// log_softmax). One 64-thread wave per node, NPB nodes per 256-thread block.
// Gather phase: lane f < DIN computes agg[f] = max over neighbors (LDS row),
// and stages the node's own row. Dense phase: lane j < CD computes the output.
// MODE: 0 = relu, 1 = none, 2 = log_softmax (final layer).
template <int DIN, int MODE>
__global__ void sage_layer_kernel(const float* __restrict__ h,
                                  const int* __restrict__ offsets,
                                  const int* __restrict__ csr_src,
                                  const float* __restrict__ Wl,
                                  const float* __restrict__ bl,
                                  const float* __restrict__ Wr,
                                  float* __restrict__ out) {
    __shared__ float sWl[DIN * CD];
    __shared__ float sWr[DIN * CD];
    __shared__ float sb[CD];
    __shared__ float sAgg[NPB][DIN];
    __shared__ float sH[NPB][DIN];

    const int tid = threadIdx.x;
    for (int i = tid; i < DIN * CD; i += blockDim.x) {
        sWl[i] = Wl[i];
        sWr[i] = Wr[i];
    }
    if (tid < CD) sb[tid] = bl[tid];

    const int g    = tid >> 6;        // wave id = local node
    const int lane = tid & 63;
    const int n    = blockIdx.x * NPB + g;

    if (n < NN && lane < DIN) {
        const int beg = offsets[n];
        const int end = offsets[n + 1];
        float acc = -INFINITY;
        for (int i = beg; i < end; ++i) {
            int s = csr_src[i];                       // wave-uniform → broadcast
            acc = fmaxf(acc, h[(size_t)s * DIN + lane]);
        }
        sAgg[g][lane] = (acc == -INFINITY) ? 0.0f : acc;  // empty segment -> 0
        sH[g][lane]   = h[(size_t)n * DIN + lane];
    }
    __syncthreads();

    if (n < NN && lane < CD) {
        float acc = sb[lane];
#pragma unroll
        for (int k = 0; k < DIN; ++k) {
            acc += sAgg[g][k] * sWl[k * CD + lane] + sH[g][k] * sWr[k * CD + lane];
        }
        if (MODE == 0) acc = fmaxf(acc, 0.0f);
        if (MODE == 2) {
            float m = acc;
            for (int off = 16; off > 0; off >>= 1) m = fmaxf(m, __shfl_xor(m, off, 32));
            float ex = expf(acc - m);
            float s = ex;
            for (int off = 16; off > 0; off >>= 1) s += __shfl_xor(s, off, 32);
            acc = acc - m - logf(s);
        }
        out[(size_t)n * CD + lane] = acc;
    }
}

// ---------------------------------------------------------------------------
extern "C" void kernel_launch(void* const* d_in, const int* in_sizes, int n_in,
                              void* d_out, int out_size, void* d_ws, size_t ws_size,
                              hipStream_t stream) {
    const float* x    = (const float*)d_in[0];
    const void*  edge = d_in[1];
    const float* Wl1 = (const float*)d_in[2];
    const float* bl1 = (const float*)d_in[3];
    const float* Wr1 = (const float*)d_in[4];
    const float* Wl2 = (const float*)d_in[5];
    const float* bl2 = (const float*)d_in[6];
    const float* Wr2 = (const float*)d_in[7];
    const float* Wl3 = (const float*)d_in[8];
    const float* bl3 = (const float*)d_in[9];
    const float* Wr3 = (const float*)d_in[10];

    const int E = in_sizes[1] / 2;

    // Workspace carve-up (256B aligned). Total ≈ 32.8 MB:
    //   cursor/counts 400KB + offsets 400KB + flag + csr_src 6.4MB
    //   + h1 12.8MB + h2 12.8MB.  (No agg buffer — gather is fused.)
    char* ws = (char*)d_ws;
    size_t off = 0;
    auto carve = [&](size_t bytes) {
        void* p = ws + off;
        off = (off + bytes + 255) & ~(size_t)255;
        return p;
    };
    int*   counts  = (int*)  carve((size_t)NN * 4);       // aliased as cursor
    int*   cursor  = counts;
    int*   offsets = (int*)  carve((size_t)(NN + 1) * 4);
    int*   flag    = (int*)  carve(4);
    int*   csr_src = (int*)  carve((size_t)E * 4);
    float* h1      = (float*)carve((size_t)NN * CD * 4);
    float* h2      = (float*)carve((size_t)NN * CD * 4);
    float* out     = (float*)d_out;
    (void)ws_size; (void)n_in; (void)out_size;

    hipMemsetAsync(counts, 0, (size_t)NN * 4, stream);
    detect_idx64<<<1, 1, 0, stream>>>(edge, flag);

    const int eb = (E + 255) / 256;
    hist_kernel<<<eb, 256, 0, stream>>>(edge, E, flag, counts);
    scan_kernel<<<1, 256, 0, stream>>>(counts, offsets, cursor);
    fill_kernel<<<eb, 256, 0, stream>>>(edge, E, flag, cursor, csr_src);

    const int nb = (NN + NPB - 1) / NPB;   // 25000 blocks, 4 nodes each

    sage_layer_kernel<50, 0><<<nb, 256, 0, stream>>>(x,  offsets, csr_src, Wl1, bl1, Wr1, h1);
    sage_layer_kernel<32, 0><<<nb, 256, 0, stream>>>(h1, offsets, csr_src, Wl2, bl2, Wr2, h2);
    sage_layer_kernel<32, 2><<<nb, 256, 0, stream>>>(h2, offsets, csr_src, Wl3, bl3, Wr3, out);
}

// Round 3
// 695.478 us; speedup vs baseline: 1.3133x; 1.3133x over previous
//
#include <hip/hip_runtime.h>
#include <math.h>

#define NN 100000      // nodes
#define CD 32          // classes / hidden
#define NPB 4          // nodes per block in fused layer kernel (1 wave each)

#define SCAN_EPB 512                                   // counts per scan block
#define SCAN_NB  ((NN + SCAN_EPB - 1) / SCAN_EPB)      // 196 blocks

// ---------------------------------------------------------------------------
// Detect whether edge_index is int64 or int32 on-device (JAX x64-off makes it
// int32 despite the reference saying int64). One wave checks 512 values.
__global__ void detect_idx64(const void* edge, int* flag) {
    const long long* p = (const long long*)edge;
    int lane = threadIdx.x & 63;
    int bad = 0;
    for (int i = lane; i < 512; i += 64) {
        long long v = p[i];
        if (v < 0 || v >= NN) bad = 1;
    }
    unsigned long long anybad = __ballot(bad);
    if (lane == 0) *flag = (anybad == 0ULL) ? 1 : 0;
}

__device__ __forceinline__ int load_idx(const void* edge, int i, int is64) {
    if (is64) return (int)((const long long*)edge)[i];
    return ((const int*)edge)[i];
}

// ---------------------------------------------------------------------------
// CSR build: histogram of dst, parallel exclusive scan, scatter src ids.
// NOTE: `cursor` aliases `counts` (each counts[] address is read and later
// written by exactly one thread in scan_final — safe, saves 400 KB of ws).
__global__ void hist_kernel(const void* edge, int E, const int* flag, int* counts) {
    int e = blockIdx.x * blockDim.x + threadIdx.x;
    if (e >= E) return;
    int is64 = *flag;
    int dst = load_idx(edge, E + e, is64);
    atomicAdd(&counts[dst], 1);
}

// Phase a: per-block reduction of 512 counts -> blockSums[b].
__global__ void scan_partial_kernel(const int* __restrict__ counts,
                                    int* __restrict__ blockSums) {
    __shared__ int red[256];
    const int b = blockIdx.x, t = threadIdx.x;
    const int base = b * SCAN_EPB + t * 2;
    int s = 0;
    if (base < NN)     s += counts[base];
    if (base + 1 < NN) s += counts[base + 1];
    red[t] = s;
    __syncthreads();
    for (int off = 128; off > 0; off >>= 1) {
        if (t < off) red[t] += red[t + off];
        __syncthreads();
    }
    if (t == 0) blockSums[b] = red[0];
}

// Phase b: exclusive scan of the 196 block sums (tiny, single block).
__global__ void scan_bases_kernel(int* blockSums) {
    __shared__ int tmp[SCAN_NB];
    const int t = threadIdx.x;
    if (t < SCAN_NB) tmp[t] = blockSums[t];
    __syncthreads();
    if (t == 0) {
        int run = 0;
        for (int i = 0; i < SCAN_NB; ++i) { int c = tmp[i]; tmp[i] = run; run += c; }
    }
    __syncthreads();
    if (t < SCAN_NB) blockSums[t] = tmp[t];
}

// Phase c: per-block Hillis-Steele scan + base -> offsets & cursor.
__global__ void scan_final_kernel(const int* __restrict__ counts,
                                  const int* __restrict__ blockSums,
                                  int* __restrict__ offsets,
                                  int* __restrict__ cursor) {
    __shared__ int tsum[256];
    const int b = blockIdx.x, t = threadIdx.x;
    const int base = b * SCAN_EPB + t * 2;
    const int c0 = (base < NN)     ? counts[base]     : 0;
    const int c1 = (base + 1 < NN) ? counts[base + 1] : 0;
    tsum[t] = c0 + c1;
    __syncthreads();
    for (int off = 1; off < 256; off <<= 1) {     // inclusive scan
        int u = (t >= off) ? tsum[t - off] : 0;
        __syncthreads();
        tsum[t] += u;
        __syncthreads();
    }
    const int bbase = blockSums[b];
    const int excl  = tsum[t] - (c0 + c1);
    if (base < NN) {
        int o = bbase + excl;
        offsets[base] = o; cursor[base] = o;
        if (base + 1 < NN) {
            int o1 = o + c0;
            offsets[base + 1] = o1; cursor[base + 1] = o1;
        }
    }
    if (b == SCAN_NB - 1 && t == 255) offsets[NN] = bbase + tsum[255];  // == E
}

__global__ void fill_kernel(const void* edge, int E, const int* flag,
                            int* cursor, int* __restrict__ csr_src) {
    int e = blockIdx.x * blockDim.x + threadIdx.x;
    if (e >= E) return;
    int is64 = *flag;
    int s = load_idx(edge, e, is64);
    int d = load_idx(edge, E + e, is64);
    int pos = atomicAdd(&cursor[d], 1);
    csr_src[pos] = s;
}

// ---------------------------------------------------------------------------
// Fused SAGE layer: gather-max over neighbors + dual dense (+ optional relu /
// log_softmax). One 64-thread wave per node, NPB nodes per 256-thread block.
// MODE: 0 = relu, 2 = log_softmax (final layer).
template <int DIN, int MODE>
__global__ void sage_layer_kernel(const float* __restrict__ h,
                                  const int* __restrict__ offsets,
                                  const int* __restrict__ csr_src,
                                  const float* __restrict__ Wl,
                                  const float* __restrict__ bl,
                                  const float* __restrict__ Wr,
                                  float* __restrict__ out) {
    __shared__ float sWl[DIN * CD];
    __shared__ float sWr[DIN * CD];
    __shared__ float sb[CD];
    __shared__ float sAgg[NPB][DIN];
    __shared__ float sH[NPB][DIN];

    const int tid = threadIdx.x;
    for (int i = tid; i < DIN * CD; i += blockDim.x) {
        sWl[i] = Wl[i];
        sWr[i] = Wr[i];
    }
    if (tid < CD) sb[tid] = bl[tid];

    const int g    = tid >> 6;        // wave id = local node
    const int lane = tid & 63;
    const int n    = blockIdx.x * NPB + g;

    if (n < NN && lane < DIN) {
        const int beg = offsets[n];
        const int end = offsets[n + 1];
        float acc = -INFINITY;
        for (int i = beg; i < end; ++i) {
            int s = csr_src[i];
            acc = fmaxf(acc, h[(size_t)s * DIN + lane]);
        }
        sAgg[g][lane] = (acc == -INFINITY) ? 0.0f : acc;  // empty segment -> 0
        sH[g][lane]   = h[(size_t)n * DIN + lane];
    }
    __syncthreads();

    if (n < NN && lane < CD) {
        float acc = sb[lane];
#pragma unroll
        for (int k = 0; k < DIN; ++k) {
            acc += sAgg[g][k] * sWl[k * CD + lane] + sH[g][k] * sWr[k * CD + lane];
        }
        if (MODE == 0) acc = fmaxf(acc, 0.0f);
        if (MODE == 2) {
            float m = acc;
            for (int off = 16; off > 0; off >>= 1) m = fmaxf(m, __shfl_xor(m, off, 32));
            float ex = expf(acc - m);
            float s = ex;
            for (int off = 16; off > 0; off >>= 1) s += __shfl_xor(s, off, 32);
            acc = acc - m - logf(s);
        }
        out[(size_t)n * CD + lane] = acc;
    }
}

// ---------------------------------------------------------------------------
extern "C" void kernel_launch(void* const* d_in, const int* in_sizes, int n_in,
                              void* d_out, int out_size, void* d_ws, size_t ws_size,
                              hipStream_t stream) {
    const float* x    = (const float*)d_in[0];
    const void*  edge = d_in[1];
    const float* Wl1 = (const float*)d_in[2];
    const float* bl1 = (const float*)d_in[3];
    const float* Wr1 = (const float*)d_in[4];
    const float* Wl2 = (const float*)d_in[5];
    const float* bl2 = (const float*)d_in[6];
    const float* Wr2 = (const float*)d_in[7];
    const float* Wl3 = (const float*)d_in[8];
    const float* bl3 = (const float*)d_in[9];
    const float* Wr3 = (const float*)d_in[10];

    const int E = in_sizes[1] / 2;

    // Workspace carve-up (256B aligned). Total ≈ 32.8 MB.
    char* ws = (char*)d_ws;
    size_t off = 0;
    auto carve = [&](size_t bytes) {
        void* p = ws + off;
        off = (off + bytes + 255) & ~(size_t)255;
        return p;
    };
    int*   counts    = (int*)  carve((size_t)NN * 4);       // aliased as cursor
    int*   cursor    = counts;
    int*   offsets   = (int*)  carve((size_t)(NN + 1) * 4);
    int*   flag      = (int*)  carve(4);
    int*   blockSums = (int*)  carve((size_t)SCAN_NB * 4);
    int*   csr_src   = (int*)  carve((size_t)E * 4);
    float* h1        = (float*)carve((size_t)NN * CD * 4);
    float* h2        = (float*)carve((size_t)NN * CD * 4);
    float* out       = (float*)d_out;
    (void)ws_size; (void)n_in; (void)out_size;

    hipMemsetAsync(counts, 0, (size_t)NN * 4, stream);
    detect_idx64<<<1, 64, 0, stream>>>(edge, flag);

    const int eb = (E + 255) / 256;
    hist_kernel<<<eb, 256, 0, stream>>>(edge, E, flag, counts);
    scan_partial_kernel<<<SCAN_NB, 256, 0, stream>>>(counts, blockSums);
    scan_bases_kernel<<<1, 256, 0, stream>>>(blockSums);
    scan_final_kernel<<<SCAN_NB, 256, 0, stream>>>(counts, blockSums, offsets, cursor);
    fill_kernel<<<eb, 256, 0, stream>>>(edge, E, flag, cursor, csr_src);

    const int nb = (NN + NPB - 1) / NPB;   // 25000 blocks, 4 nodes each

    sage_layer_kernel<50, 0><<<nb, 256, 0, stream>>>(x,  offsets, csr_src, Wl1, bl1, Wr1, h1);
    sage_layer_kernel<32, 0><<<nb, 256, 0, stream>>>(h1, offsets, csr_src, Wl2, bl2, Wr2, h2);
    sage_layer_kernel<32, 2><<<nb, 256, 0, stream>>>(h2, offsets, csr_src, Wl3, bl3, Wr3, out);
}

// Round 4
// 585.211 us; speedup vs baseline: 1.5607x; 1.1884x over previous
//
#include <hip/hip_runtime.h>
#include <math.h>

#define NN 100000      // nodes
#define CD 32          // classes / hidden
#define NPB 4          // nodes per block in fused layer kernel (1 wave each)

#define SCAN_EPB 512                                   // counts per scan block
#define SCAN_NB  ((NN + SCAN_EPB - 1) / SCAN_EPB)      // 196 blocks

// ---------------------------------------------------------------------------
// Detect whether edge_index is int64 or int32 on-device (JAX x64-off makes it
// int32 despite the reference saying int64). One wave checks 512 values.
__global__ void detect_idx64(const void* edge, int* flag) {
    const long long* p = (const long long*)edge;
    int lane = threadIdx.x & 63;
    int bad = 0;
    for (int i = lane; i < 512; i += 64) {
        long long v = p[i];
        if (v < 0 || v >= NN) bad = 1;
    }
    unsigned long long anybad = __ballot(bad);
    if (lane == 0) *flag = (anybad == 0ULL) ? 1 : 0;
}

__device__ __forceinline__ int load_idx(const void* edge, int i, int is64) {
    if (is64) return (int)((const long long*)edge)[i];
    return ((const int*)edge)[i];
}

// ---------------------------------------------------------------------------
// CSR build: histogram of dst, parallel exclusive scan, scatter src ids.
// `cursor` aliases `counts` (each address read+written by exactly one thread).
__global__ void hist_kernel(const void* edge, int E, const int* flag, int* counts) {
    int e = blockIdx.x * blockDim.x + threadIdx.x;
    if (e >= E) return;
    int is64 = *flag;
    int dst = load_idx(edge, E + e, is64);
    atomicAdd(&counts[dst], 1);
}

__global__ void scan_partial_kernel(const int* __restrict__ counts,
                                    int* __restrict__ blockSums) {
    __shared__ int red[256];
    const int b = blockIdx.x, t = threadIdx.x;
    const int base = b * SCAN_EPB + t * 2;
    int s = 0;
    if (base < NN)     s += counts[base];
    if (base + 1 < NN) s += counts[base + 1];
    red[t] = s;
    __syncthreads();
    for (int off = 128; off > 0; off >>= 1) {
        if (t < off) red[t] += red[t + off];
        __syncthreads();
    }
    if (t == 0) blockSums[b] = red[0];
}

__global__ void scan_bases_kernel(int* blockSums) {
    __shared__ int tmp[SCAN_NB];
    const int t = threadIdx.x;
    if (t < SCAN_NB) tmp[t] = blockSums[t];
    __syncthreads();
    if (t == 0) {
        int run = 0;
        for (int i = 0; i < SCAN_NB; ++i) { int c = tmp[i]; tmp[i] = run; run += c; }
    }
    __syncthreads();
    if (t < SCAN_NB) blockSums[t] = tmp[t];
}

__global__ void scan_final_kernel(const int* __restrict__ counts,
                                  const int* __restrict__ blockSums,
                                  int* __restrict__ offsets,
                                  int* __restrict__ cursor) {
    __shared__ int tsum[256];
    const int b = blockIdx.x, t = threadIdx.x;
    const int base = b * SCAN_EPB + t * 2;
    const int c0 = (base < NN)     ? counts[base]     : 0;
    const int c1 = (base + 1 < NN) ? counts[base + 1] : 0;
    tsum[t] = c0 + c1;
    __syncthreads();
    for (int off = 1; off < 256; off <<= 1) {
        int u = (t >= off) ? tsum[t - off] : 0;
        __syncthreads();
        tsum[t] += u;
        __syncthreads();
    }
    const int bbase = blockSums[b];
    const int excl  = tsum[t] - (c0 + c1);
    if (base < NN) {
        int o = bbase + excl;
        offsets[base] = o; cursor[base] = o;
        if (base + 1 < NN) {
            int o1 = o + c0;
            offsets[base + 1] = o1; cursor[base + 1] = o1;
        }
    }
    if (b == SCAN_NB - 1 && t == 255) offsets[NN] = bbase + tsum[255];  // == E
}

__global__ void fill_kernel(const void* edge, int E, const int* flag,
                            int* cursor, int* __restrict__ csr_src) {
    int e = blockIdx.x * blockDim.x + threadIdx.x;
    if (e >= E) return;
    int is64 = *flag;
    int s = load_idx(edge, e, is64);
    int d = load_idx(edge, E + e, is64);
    int pos = atomicAdd(&cursor[d], 1);
    csr_src[pos] = s;
}

// ---------------------------------------------------------------------------
// Fused SAGE layer: gather-max over neighbors + dual dense (+ relu / log_sm).
// One 64-lane wave per node, NPB nodes per 256-thread block.
// Gather: unroll x4 for MLP; DIN==32 additionally packs 2 neighbors per wave.
// Dense: k-loop split across wave halves, combined with one 64-wide shfl.
// MODE: 0 = relu, 2 = log_softmax (final layer).
template <int DIN, int MODE>
__global__ void sage_layer_kernel(const float* __restrict__ h,
                                  const int* __restrict__ offsets,
                                  const int* __restrict__ csr_src,
                                  const float* __restrict__ Wl,
                                  const float* __restrict__ bl,
                                  const float* __restrict__ Wr,
                                  float* __restrict__ out) {
    __shared__ float sWl[DIN * CD];
    __shared__ float sWr[DIN * CD];
    __shared__ float sb[CD];
    __shared__ float sAgg[NPB][DIN];
    __shared__ float sH[NPB][DIN];

    const int tid = threadIdx.x;
    for (int i = tid; i < DIN * CD; i += blockDim.x) {
        sWl[i] = Wl[i];
        sWr[i] = Wr[i];
    }
    if (tid < CD) sb[tid] = bl[tid];

    const int g    = tid >> 6;        // wave id = local node
    const int lane = tid & 63;
    const int n    = blockIdx.x * NPB + g;

    if (n < NN) {
        const int beg = offsets[n];
        const int end = offsets[n + 1];
        if (DIN == 32) {
            // 2 neighbors per wave: lane = p*32 + j; unroll x2 per half.
            const int p = lane >> 5;
            const int j = lane & 31;
            float a0 = -INFINITY, a1 = -INFINITY;
            int i = beg + p;
            for (; i + 2 < end; i += 4) {
                int s0 = csr_src[i];
                int s1 = csr_src[i + 2];
                a0 = fmaxf(a0, h[(size_t)s0 * 32 + j]);
                a1 = fmaxf(a1, h[(size_t)s1 * 32 + j]);
            }
            for (; i < end; i += 2)
                a0 = fmaxf(a0, h[(size_t)csr_src[i] * 32 + j]);
            float a = fmaxf(a0, a1);
            a = fmaxf(a, __shfl_xor(a, 32));          // combine halves
            if (lane < 32) {
                sAgg[g][j] = (a == -INFINITY) ? 0.0f : a;
                sH[g][j]   = h[(size_t)n * 32 + j];
            }
        } else {
            if (lane < DIN) {
                float a0 = -INFINITY, a1 = -INFINITY, a2 = -INFINITY, a3 = -INFINITY;
                int i = beg;
                for (; i + 4 <= end; i += 4) {
                    int s0 = csr_src[i],     s1 = csr_src[i + 1];
                    int s2 = csr_src[i + 2], s3 = csr_src[i + 3];
                    a0 = fmaxf(a0, h[(size_t)s0 * DIN + lane]);
                    a1 = fmaxf(a1, h[(size_t)s1 * DIN + lane]);
                    a2 = fmaxf(a2, h[(size_t)s2 * DIN + lane]);
                    a3 = fmaxf(a3, h[(size_t)s3 * DIN + lane]);
                }
                for (; i < end; ++i)
                    a0 = fmaxf(a0, h[(size_t)csr_src[i] * DIN + lane]);
                float a = fmaxf(fmaxf(a0, a1), fmaxf(a2, a3));
                sAgg[g][lane] = (a == -INFINITY) ? 0.0f : a;
                sH[g][lane]   = h[(size_t)n * DIN + lane];
            }
        }
    }
    __syncthreads();

    if (n < NN) {
        // Dense: halves of the wave split the k-range, shfl-combine.
        const int p  = lane >> 5;
        const int j  = lane & 31;
        const int KH = DIN / 2;                  // 25 or 16
        const int k0 = p * KH;
        const int k1 = (p == 1) ? DIN : KH;      // second half takes remainder
        float part = (p == 0) ? sb[j] : 0.0f;
#pragma unroll
        for (int k = k0; k < k1; ++k) {
            part += sAgg[g][k] * sWl[k * CD + j] + sH[g][k] * sWr[k * CD + j];
        }
        float acc = part + __shfl_xor(part, 32);
        if (lane < 32) {
            if (MODE == 0) acc = fmaxf(acc, 0.0f);
            if (MODE == 2) {
                float m = acc;
                for (int off = 16; off > 0; off >>= 1) m = fmaxf(m, __shfl_xor(m, off, 32));
                float ex = expf(acc - m);
                float s = ex;
                for (int off = 16; off > 0; off >>= 1) s += __shfl_xor(s, off, 32);
                acc = acc - m - logf(s);
            }
            out[(size_t)n * CD + j] = acc;
        }
    }
}

// ---------------------------------------------------------------------------
extern "C" void kernel_launch(void* const* d_in, const int* in_sizes, int n_in,
                              void* d_out, int out_size, void* d_ws, size_t ws_size,
                              hipStream_t stream) {
    const float* x    = (const float*)d_in[0];
    const void*  edge = d_in[1];
    const float* Wl1 = (const float*)d_in[2];
    const float* bl1 = (const float*)d_in[3];
    const float* Wr1 = (const float*)d_in[4];
    const float* Wl2 = (const float*)d_in[5];
    const float* bl2 = (const float*)d_in[6];
    const float* Wr2 = (const float*)d_in[7];
    const float* Wl3 = (const float*)d_in[8];
    const float* bl3 = (const float*)d_in[9];
    const float* Wr3 = (const float*)d_in[10];

    const int E = in_sizes[1] / 2;

    // Workspace carve-up (256B aligned). Total ≈ 32.8 MB.
    char* ws = (char*)d_ws;
    size_t off = 0;
    auto carve = [&](size_t bytes) {
        void* p = ws + off;
        off = (off + bytes + 255) & ~(size_t)255;
        return p;
    };
    int*   counts    = (int*)  carve((size_t)NN * 4);       // aliased as cursor
    int*   cursor    = counts;
    int*   offsets   = (int*)  carve((size_t)(NN + 1) * 4);
    int*   flag      = (int*)  carve(4);
    int*   blockSums = (int*)  carve((size_t)SCAN_NB * 4);
    int*   csr_src   = (int*)  carve((size_t)E * 4);
    float* h1        = (float*)carve((size_t)NN * CD * 4);
    float* h2        = (float*)carve((size_t)NN * CD * 4);
    float* out       = (float*)d_out;
    (void)ws_size; (void)n_in; (void)out_size;

    hipMemsetAsync(counts, 0, (size_t)NN * 4, stream);
    detect_idx64<<<1, 64, 0, stream>>>(edge, flag);

    const int eb = (E + 255) / 256;
    hist_kernel<<<eb, 256, 0, stream>>>(edge, E, flag, counts);
    scan_partial_kernel<<<SCAN_NB, 256, 0, stream>>>(counts, blockSums);
    scan_bases_kernel<<<1, 256, 0, stream>>>(blockSums);
    scan_final_kernel<<<SCAN_NB, 256, 0, stream>>>(counts, blockSums, offsets, cursor);
    fill_kernel<<<eb, 256, 0, stream>>>(edge, E, flag, cursor, csr_src);

    const int nb = (NN + NPB - 1) / NPB;   // 25000 blocks, 4 nodes each

    sage_layer_kernel<50, 0><<<nb, 256, 0, stream>>>(x,  offsets, csr_src, Wl1, bl1, Wr1, h1);
    sage_layer_kernel<32, 0><<<nb, 256, 0, stream>>>(h1, offsets, csr_src, Wl2, bl2, Wr2, h2);
    sage_layer_kernel<32, 2><<<nb, 256, 0, stream>>>(h2, offsets, csr_src, Wl3, bl3, Wr3, out);
}